// Round 8
// baseline (429.821 us; speedup 1.0000x reference)
//
#include <hip/hip_runtime.h>

// MultiHeadAttention fwd: B=4, S=2048, D=1024, H=16, DK=64.
// Round 7 (resubmit; round-7 bench hit GPUAcquisitionTimeout):
// (1) attn softmax in log2 domain (exp2f native), defer-max THR=8,
// 4-way parallel reduce chains; (2) QKV GEMMs fused into one dispatch reading
// f32 inputs directly (on-the-fly RNE cast in A-staging) — cast kernels gone;
// (3) wtrans fused. 5 dispatches total.
// ws layout (75.5 MB, unchanged): 4x WT bf16 [N][K] | Vt(old Xb slot) | Qp | Kp | Vp(->ctx)

#define B_ 4
#define S_ 2048
#define D_ 1024
#define H_ 16
#define M_ 8192  // B_*S_

typedef unsigned short u16;
typedef unsigned int u32;
typedef float f32x4 __attribute__((ext_vector_type(4)));
typedef float f32x16 __attribute__((ext_vector_type(16)));
typedef __bf16 bf16x8 __attribute__((ext_vector_type(8)));
typedef u32 u32x2 __attribute__((ext_vector_type(2)));
typedef u32 u32x4 __attribute__((ext_vector_type(4)));

__device__ __forceinline__ u16 f2bf(float f) {
  unsigned int x = __float_as_uint(f);
  x = (x + 0x7fffu + ((x >> 16) & 1u)) >> 16;  // RNE
  return (u16)x;
}

__device__ __forceinline__ f32x4 mfma16(bf16x8 a, bf16x8 b, f32x4 c) {
  return __builtin_amdgcn_mfma_f32_16x16x32_bf16(a, b, c, 0, 0, 0);
}
__device__ __forceinline__ f32x16 mfma32(bf16x8 a, bf16x8 b, f32x16 c) {
  return __builtin_amdgcn_mfma_f32_32x32x16_bf16(a, b, c, 0, 0, 0);
}
// packs (lo,hi) -> u32 of 2 bf16 (low=lo), RNE
__device__ __forceinline__ u32 cvtpk_bf16(float lo, float hi) {
  u32 r;
  asm("v_cvt_pk_bf16_f32 %0, %1, %2" : "=v"(r) : "v"(lo), "v"(hi));
  return r;
}
__device__ __forceinline__ void gload_lds16(const u16* g, u16* l) {
  __builtin_amdgcn_global_load_lds((const __attribute__((address_space(1))) void*)g,
                                   (__attribute__((address_space(3))) void*)l, 16, 0, 0);
}

// ---------------- W [K][N] f32 -> WT [N][K] bf16 (all 4 weights, z-indexed) ----
__global__ __launch_bounds__(256) void wtrans_kernel(
    const float* __restrict__ W0, const float* __restrict__ W1,
    const float* __restrict__ W2, const float* __restrict__ W3,
    u16* __restrict__ T0, u16* __restrict__ T1,
    u16* __restrict__ T2, u16* __restrict__ T3) {
  __shared__ float tile[32][33];
  int z = blockIdx.z;
  const float* W = z == 0 ? W0 : z == 1 ? W1 : z == 2 ? W2 : W3;
  u16* WT = z == 0 ? T0 : z == 1 ? T1 : z == 2 ? T2 : T3;
  int k0 = blockIdx.x * 32, n0 = blockIdx.y * 32;
  int t = threadIdx.x, c = t & 31, r0 = t >> 5;
#pragma unroll
  for (int i = 0; i < 4; ++i)
    tile[r0 + i * 8][c] = W[(size_t)(k0 + r0 + i * 8) * D_ + n0 + c];
  __syncthreads();
#pragma unroll
  for (int i = 0; i < 4; ++i)
    WT[(size_t)(n0 + r0 + i * 8) * D_ + k0 + c] = f2bf(tile[c][r0 + i * 8]);
}

// ---------------- Vp [M][D] bf16 -> Vt [64 bh][64 dk][2048 s] ----------------
__global__ __launch_bounds__(256) void vtrans_kernel(const u16* __restrict__ Vp,
                                                     u16* __restrict__ Vt) {
  __shared__ u16 tile[64][65];
  int bx = blockIdx.x;  // 64 bh * 32 s-tiles
  int bh = bx >> 5;
  int s0 = (bx & 31) * 64;
  int b = bh >> 4, h = bh & 15;
  int t = threadIdx.x, c = t & 63, r0 = t >> 6;
#pragma unroll
  for (int i = 0; i < 16; ++i) {
    int s = r0 + i * 4;
    tile[s][c] = Vp[(size_t)(b * S_ + s0 + s) * D_ + h * 64 + c];
  }
  __syncthreads();
#pragma unroll
  for (int i = 0; i < 16; ++i) {
    int dk = r0 + i * 4;
    Vt[((size_t)bh * 64 + dk) * S_ + s0 + c] = tile[c][dk];
  }
}

// ---------------- Fused QKV GEMM: out_y[M][1024] = A_y(f32) @ WT_y^T + b_y ----
// 128x128 tile, BK=64, 4 waves. A staged f32->bf16 in-flight (float4 ->
// 2x cvt_pk -> ds_write_b64, linear LDS); B staged via global_load_lds w=16.
__global__ __launch_bounds__(256) void gemm_qkv_kernel(
    const float* __restrict__ Aq, const float* __restrict__ Ak, const float* __restrict__ Av,
    const u16* __restrict__ BTq, const u16* __restrict__ BTk, const u16* __restrict__ BTv,
    const float* __restrict__ bq, const float* __restrict__ bk, const float* __restrict__ bv,
    u16* __restrict__ oq, u16* __restrict__ ok, u16* __restrict__ ov) {
  __shared__ __align__(16) u16 ldsA[128 * 64];
  __shared__ __align__(16) u16 ldsB[128 * 64];
  int y = blockIdx.y;
  const float* A  = y == 0 ? Aq : y == 1 ? Ak : Av;
  const u16* BT   = y == 0 ? BTq : y == 1 ? BTk : BTv;
  const float* bias = y == 0 ? bq : y == 1 ? bk : bv;
  u16* out        = y == 0 ? oq : y == 1 ? ok : ov;

  int bx = blockIdx.x;                  // 512 = 64 Mtiles * 8 Ntiles
  int swz = (bx & 7) * 64 + (bx >> 3);  // bijective XCD swizzle (512%8==0)
  int bm = swz >> 3, bn = swz & 7;
  int t = threadIdx.x, w = t >> 6, lane = t & 63;
  int wm = w >> 1, wn = w & 1;
  int l15 = lane & 15, hi = lane >> 4;

  f32x4 acc[4][4];
#pragma unroll
  for (int m = 0; m < 4; ++m)
#pragma unroll
    for (int n = 0; n < 4; ++n) acc[m][n] = (f32x4){0.f, 0.f, 0.f, 0.f};

  // B staging: wave w owns rows [w*32, w*32+32), lane -> linear LDS via HW
  int srow = w * 32 + (lane >> 3);
  int schunk = lane & 7;
  const u16* Bg = BT + (size_t)(bn * 128 + srow) * D_ + schunk * 8;
  u16* lB = ldsB + w * 32 * 64;  // wave-uniform LDS base

  // A staging: 16 threads/row, 8 row-passes; float4 -> 4 bf16 -> ds_write_b64
  int arow = t >> 4, ac = t & 15;
  const float* Ag = A + (size_t)(bm * 128 + arow) * D_ + ac * 4;

  for (int kk = 0; kk < D_; kk += 64) {
    __syncthreads();
#pragma unroll
    for (int i = 0; i < 4; ++i)
      gload_lds16(Bg + kk + i * 8 * D_, lB + i * 8 * 64);
#pragma unroll
    for (int p = 0; p < 8; ++p) {
      float4 v = *(const float4*)(Ag + kk + (size_t)p * 16 * D_);
      u32x2 pk;
      pk[0] = cvtpk_bf16(v.x, v.y);
      pk[1] = cvtpk_bf16(v.z, v.w);
      *(u32x2*)(ldsA + (arow + p * 16) * 64 + ac * 4) = pk;
    }
    __syncthreads();
#pragma unroll
    for (int ks = 0; ks < 2; ++ks) {
      bf16x8 af[4], bfr[4];
#pragma unroll
      for (int m = 0; m < 4; ++m)
        af[m] = *(const bf16x8*)(ldsA + (wm * 64 + m * 16 + l15) * 64 + (ks * 4 + hi) * 8);
#pragma unroll
      for (int n = 0; n < 4; ++n)
        bfr[n] = *(const bf16x8*)(ldsB + (wn * 64 + n * 16 + l15) * 64 + (ks * 4 + hi) * 8);
#pragma unroll
      for (int m = 0; m < 4; ++m)
#pragma unroll
        for (int n = 0; n < 4; ++n)
          acc[m][n] = mfma16(af[m], bfr[n], acc[m][n]);
    }
  }

#pragma unroll
  for (int m = 0; m < 4; ++m)
#pragma unroll
    for (int n = 0; n < 4; ++n) {
      int row = bm * 128 + wm * 64 + m * 16 + hi * 4;
      int col = bn * 128 + wn * 64 + n * 16 + l15;
      float bv2 = bias[col];
#pragma unroll
      for (int r = 0; r < 4; ++r)
        out[(size_t)(row + r) * D_ + col] = f2bf(acc[m][n][r] + bv2);
    }
}

// ---------------- O-projection GEMM: d_out[M][1024] = ctx(bf16) @ WTo^T + bo --
__global__ __launch_bounds__(256) void gemm_o_kernel(const u16* __restrict__ A,
                                                     const u16* __restrict__ BT,
                                                     const float* __restrict__ bias,
                                                     float* __restrict__ out) {
  __shared__ __align__(16) u16 ldsA[128 * 64];
  __shared__ __align__(16) u16 ldsB[128 * 64];
  int bx = blockIdx.x;
  int swz = (bx & 7) * 64 + (bx >> 3);
  int bm = swz >> 3, bn = swz & 7;
  int t = threadIdx.x, w = t >> 6, lane = t & 63;
  int wm = w >> 1, wn = w & 1;
  int l15 = lane & 15, hi = lane >> 4;

  f32x4 acc[4][4];
#pragma unroll
  for (int m = 0; m < 4; ++m)
#pragma unroll
    for (int n = 0; n < 4; ++n) acc[m][n] = (f32x4){0.f, 0.f, 0.f, 0.f};

  int srow = w * 32 + (lane >> 3);
  int schunk = lane & 7;
  const u16* Ag = A + (size_t)(bm * 128 + srow) * D_ + schunk * 8;
  const u16* Bg = BT + (size_t)(bn * 128 + srow) * D_ + schunk * 8;
  u16* lA = ldsA + w * 32 * 64;
  u16* lB = ldsB + w * 32 * 64;

  for (int kk = 0; kk < D_; kk += 64) {
    __syncthreads();
#pragma unroll
    for (int i = 0; i < 4; ++i) {
      gload_lds16(Ag + kk + i * 8 * D_, lA + i * 8 * 64);
      gload_lds16(Bg + kk + i * 8 * D_, lB + i * 8 * 64);
    }
    __syncthreads();
#pragma unroll
    for (int ks = 0; ks < 2; ++ks) {
      bf16x8 af[4], bfr[4];
#pragma unroll
      for (int m = 0; m < 4; ++m)
        af[m] = *(const bf16x8*)(ldsA + (wm * 64 + m * 16 + l15) * 64 + (ks * 4 + hi) * 8);
#pragma unroll
      for (int n = 0; n < 4; ++n)
        bfr[n] = *(const bf16x8*)(ldsB + (wn * 64 + n * 16 + l15) * 64 + (ks * 4 + hi) * 8);
#pragma unroll
      for (int m = 0; m < 4; ++m)
#pragma unroll
        for (int n = 0; n < 4; ++n)
          acc[m][n] = mfma16(af[m], bfr[n], acc[m][n]);
    }
  }

#pragma unroll
  for (int m = 0; m < 4; ++m)
#pragma unroll
    for (int n = 0; n < 4; ++n) {
      int row = bm * 128 + wm * 64 + m * 16 + hi * 4;
      int col = bn * 128 + wn * 64 + n * 16 + l15;
      float bv = bias[col];
#pragma unroll
      for (int r = 0; r < 4; ++r)
        out[(size_t)(row + r) * D_ + col] = acc[m][n][r] + bv;
    }
}

// ---------------- Flash attention, 8 waves x 32 q-rows, 32x32 MFMA ----------------
// Swapped QK^T; softmax in log2 domain (Q pre-scaled by log2e/8, exp2f native).
// Defer-max (T13, THR=8 -> P<=256): rescale path (16 bpermute + O muls) skipped
// unless some row's tile-max exceeds running max by >8. Reduce chains split 4-way.
__global__ __launch_bounds__(512) void attn_kernel(const u16* __restrict__ Qp,
                                                   const u16* __restrict__ Kp,
                                                   const u16* __restrict__ Vt,
                                                   u16* __restrict__ ctx) {
  __shared__ __align__(16) u16 Kl[128 * 64];
  __shared__ __align__(16) u16 Vl[64 * 128];

  int bx = blockIdx.x;                 // 512 = 64 bh * 8 qtiles
  int bh = (bx & 7) * 8 + (bx >> 6);   // 8 blocks of same bh per XCD
  int qt = (bx >> 3) & 7;
  int b = bh >> 4, h = bh & 15;

  int t = threadIdx.x, w = t >> 6, lane = t & 63;
  int l31 = lane & 31, hh = lane >> 5;
  int qglob = qt * 256 + w * 32;       // wave's 32 q rows

  // Q B-frags pre-scaled by log2e/sqrt(DK) = 0.125*1.4426950 (log2-domain scores)
  bf16x8 qf[4];
  {
    const u16* qptr = Qp + (size_t)(b * S_ + qglob + l31) * D_ + h * 64;
#pragma unroll
    for (int ks = 0; ks < 4; ++ks) {
      bf16x8 v = *(const bf16x8*)(qptr + ks * 16 + hh * 8);
#pragma unroll
      for (int j = 0; j < 8; ++j) v[j] = (__bf16)((float)v[j] * 0.18033688f);
      qf[ks] = v;
    }
  }

  float m = -1e30f, l = 0.f;
  f32x16 O0, O1;
#pragma unroll
  for (int i = 0; i < 16; ++i) { O0[i] = 0.f; O1[i] = 0.f; }

  // staging (global->reg->LDS): K 128x8 chunk-slots, V 64x16; 512 threads, 2 each
  const u16* Kbase = Kp + (size_t)(b * S_) * D_ + h * 64;
  const u16* Vbase = Vt + (size_t)bh * 64 * S_;
  int krow = t >> 3, kc = t & 7;   // K rows krow, krow+64
  int vrow = t >> 4, vc = t & 15;  // V rows vrow, vrow+32
  u32x4 kreg0, kreg1, vreg0, vreg1;
  kreg0 = *(const u32x4*)(Kbase + (size_t)(krow)*D_ + kc * 8);
  kreg1 = *(const u32x4*)(Kbase + (size_t)(krow + 64) * D_ + kc * 8);
  vreg0 = *(const u32x4*)(Vbase + (size_t)(vrow)*S_ + vc * 8);
  vreg1 = *(const u32x4*)(Vbase + (size_t)(vrow + 32) * S_ + vc * 8);

  for (int kt = 0; kt < 16; ++kt) {
    __syncthreads();  // previous tile fully consumed
    // swizzled ds_writes: K chunk pi = c ^ (key&7); V pi = (c&8)|((c^dk)&7)
    *(u32x4*)(Kl + krow * 64 + ((kc ^ (krow & 7)) << 3)) = kreg0;
    *(u32x4*)(Kl + (krow + 64) * 64 + ((kc ^ (krow & 7)) << 3)) = kreg1;
    *(u32x4*)(Vl + vrow * 128 + (((vc & 8) | ((vc ^ vrow) & 7)) << 3)) = vreg0;
    *(u32x4*)(Vl + (vrow + 32) * 128 + (((vc & 8) | ((vc ^ vrow) & 7)) << 3)) = vreg1;
    if (kt < 15) {  // T14: issue next-tile loads; consumed after next barrier
      kreg0 = *(const u32x4*)(Kbase + (size_t)(kt * 128 + 128 + krow) * D_ + kc * 8);
      kreg1 = *(const u32x4*)(Kbase + (size_t)(kt * 128 + 192 + krow) * D_ + kc * 8);
      vreg0 = *(const u32x4*)(Vbase + (size_t)(vrow)*S_ + kt * 128 + 128 + vc * 8);
      vreg1 = *(const u32x4*)(Vbase + (size_t)(vrow + 32) * S_ + kt * 128 + 128 + vc * 8);
    }
    __syncthreads();  // ds_writes visible

    // ---- QK^T: 4 C-tiles of 32 keys (scores already in log2 units) ----
    f32x16 pct[4];
#pragma unroll
    for (int ct = 0; ct < 4; ++ct) {
      f32x16 p;
#pragma unroll
      for (int i = 0; i < 16; ++i) p[i] = 0.f;
#pragma unroll
      for (int ks = 0; ks < 4; ++ks) {
        int key = ct * 32 + l31;
        int cl = 2 * ks + hh;  // logical 16B chunk in K row
        bf16x8 kf = *(const bf16x8*)(Kl + key * 64 + ((cl ^ (key & 7)) << 3));
        p = mfma32(kf, qf[ks], p);
      }
      pct[ct] = p;
    }

    // ---- online softmax, log2 domain; 4-way parallel reduce chains ----
    float pm0 = -1e30f, pm1 = -1e30f, pm2 = -1e30f, pm3 = -1e30f;
#pragma unroll
    for (int i = 0; i < 16; ++i) {
      pm0 = fmaxf(pm0, pct[0][i]); pm1 = fmaxf(pm1, pct[1][i]);
      pm2 = fmaxf(pm2, pct[2][i]); pm3 = fmaxf(pm3, pct[3][i]);
    }
    float pm = fmaxf(fmaxf(pm0, pm1), fmaxf(pm2, pm3));
    pm = fmaxf(pm, __shfl_xor(pm, 32, 64));

    if (!__all(pm - m <= 8.0f)) {  // defer-max: tolerate P <= 2^8
      float mn = fmaxf(m, pm);
      float alpha = exp2f(m - mn);
      m = mn;
      l *= alpha;
#pragma unroll
      for (int i = 0; i < 16; ++i) {  // O rows are q=(i&3)+8*(i>>2)+4*hh, NOT lane-q
        float a = __shfl(alpha, (i & 3) + 8 * (i >> 2) + 4 * hh, 64);
        O0[i] *= a;
        O1[i] *= a;
      }
    }

    float ls0 = 0.f, ls1 = 0.f, ls2 = 0.f, ls3 = 0.f;
#pragma unroll
    for (int i = 0; i < 16; ++i) {
      float e0 = exp2f(pct[0][i] - m); pct[0][i] = e0; ls0 += e0;
      float e1 = exp2f(pct[1][i] - m); pct[1][i] = e1; ls1 += e1;
      float e2 = exp2f(pct[2][i] - m); pct[2][i] = e2; ls2 += e2;
      float e3 = exp2f(pct[3][i] - m); pct[3][i] = e3; ls3 += e3;
    }
    float ls = (ls0 + ls1) + (ls2 + ls3);
    l += ls + __shfl_xor(ls, 32, 64);

    // ---- repack P (T12) + PV ----
#pragma unroll
    for (int ct = 0; ct < 4; ++ct) {
#pragma unroll
      for (int ks2 = 0; ks2 < 2; ++ks2) {
        u32 A0 = cvtpk_bf16(pct[ct][8 * ks2 + 0], pct[ct][8 * ks2 + 1]);
        u32 A1 = cvtpk_bf16(pct[ct][8 * ks2 + 2], pct[ct][8 * ks2 + 3]);
        u32 B0 = cvtpk_bf16(pct[ct][8 * ks2 + 4], pct[ct][8 * ks2 + 5]);
        u32 B1 = cvtpk_bf16(pct[ct][8 * ks2 + 6], pct[ct][8 * ks2 + 7]);
        u32 s0 = __shfl_xor((int)(hh ? A0 : B0), 32, 64);
        u32 s1 = __shfl_xor((int)(hh ? A1 : B1), 32, 64);
        u32x4 fw;
        fw[0] = hh ? s0 : A0;
        fw[1] = hh ? s1 : A1;
        fw[2] = hh ? B0 : s0;
        fw[3] = hh ? B1 : s1;
        bf16x8 pf = __builtin_bit_cast(bf16x8, fw);
        int cl = ct * 4 + 2 * ks2 + hh;  // logical chunk in V row (key/8)
#pragma unroll
        for (int dkh = 0; dkh < 2; ++dkh) {
          int dk = l31 + dkh * 32;
          bf16x8 vf = *(const bf16x8*)(Vl + dk * 128 + (((cl & 8) | ((cl ^ dk) & 7)) << 3));
          if (dkh == 0) O0 = mfma32(pf, vf, O0);
          else          O1 = mfma32(pf, vf, O1);
        }
      }
    }
  }

  // ---- epilogue: normalize rows; O C-layout row q = (r&3)+8*(r>>2)+4*hh ----
#pragma unroll
  for (int r = 0; r < 16; ++r) {
    int ql = (r & 3) + 8 * (r >> 2) + 4 * hh;
    float lr = __shfl(l, ql, 64);  // l lives at lane q (both halves identical)
    float inv = 1.0f / lr;
    u16* cp = ctx + (size_t)(b * S_ + qglob + ql) * D_ + h * 64;
    cp[l31] = f2bf(O0[r] * inv);
    cp[l31 + 32] = f2bf(O1[r] * inv);
  }
}

extern "C" void kernel_launch(void* const* d_in, const int* in_sizes, int n_in,
                              void* d_out, int out_size, void* d_ws, size_t ws_size,
                              hipStream_t stream) {
  const float* query = (const float*)d_in[0];
  const float* key   = (const float*)d_in[1];
  const float* value = (const float*)d_in[2];
  const float* Wq = (const float*)d_in[3];
  const float* bq = (const float*)d_in[4];
  const float* Wk = (const float*)d_in[5];
  const float* bk = (const float*)d_in[6];
  const float* Wv = (const float*)d_in[7];
  const float* bv = (const float*)d_in[8];
  const float* Wo = (const float*)d_in[9];
  const float* bo = (const float*)d_in[10];

  char* ws = (char*)d_ws;
  const size_t WT_BYTES  = (size_t)D_ * D_ * 2;
  const size_t MAT_BYTES = (size_t)M_ * D_ * 2;
  u16* WTq = (u16*)(ws);
  u16* WTk = (u16*)(ws + WT_BYTES);
  u16* WTv = (u16*)(ws + 2 * WT_BYTES);
  u16* WTo = (u16*)(ws + 3 * WT_BYTES);
  u16* Vt  = (u16*)(ws + 4 * WT_BYTES);                  // old Xb slot
  u16* Qp  = (u16*)(ws + 4 * WT_BYTES + MAT_BYTES);
  u16* Kp  = (u16*)(ws + 4 * WT_BYTES + 2 * MAT_BYTES);
  u16* Vp  = (u16*)(ws + 4 * WT_BYTES + 3 * MAT_BYTES);
  u16* ctx = Vp;   // Vp free after vtrans

  dim3 blk(256);
  wtrans_kernel<<<dim3(32, 32, 4), blk, 0, stream>>>(Wq, Wk, Wv, Wo, WTq, WTk, WTv, WTo);
  gemm_qkv_kernel<<<dim3(512, 3), blk, 0, stream>>>(query, key, value, WTq, WTk, WTv,
                                                    bq, bk, bv, Qp, Kp, Vp);
  vtrans_kernel<<<2048, blk, 0, stream>>>(Vp, Vt);
  attn_kernel<<<512, dim3(512), 0, stream>>>(Qp, Kp, Vt, ctx);
  gemm_o_kernel<<<512, blk, 0, stream>>>(ctx, WTo, bo, (float*)d_out);
}

// Round 10
// 396.680 us; speedup vs baseline: 1.0835x; 1.0835x over previous
//
#include <hip/hip_runtime.h>

// MultiHeadAttention fwd: B=4, S=2048, D=1024, H=16, DK=64.
// Round 9 (resubmit; round-9 bench hit GPUAcquisitionTimeout):
// gemm_qkv was latency-bound (MfmaUtil 13%, VALU 16%, HBM 10% — all idle).
// Pipeline it: A f32 prefetch loads issued before the pre-compute barrier;
// raw s_barrier + counted s_waitcnt vmcnt(8) keeps the 8 A-loads in flight
// across the MFMA phase (B's 4 gload_lds are the oldest, drained).
// attn / gemm_o / vtrans / wtrans unchanged from round 8.
// ws layout (75.5 MB): 4x WT bf16 [N][K] | Vt | Qp | Kp | Vp(->ctx)

#define B_ 4
#define S_ 2048
#define D_ 1024
#define H_ 16
#define M_ 8192  // B_*S_

typedef unsigned short u16;
typedef unsigned int u32;
typedef float f32x4 __attribute__((ext_vector_type(4)));
typedef float f32x16 __attribute__((ext_vector_type(16)));
typedef __bf16 bf16x8 __attribute__((ext_vector_type(8)));
typedef u32 u32x2 __attribute__((ext_vector_type(2)));
typedef u32 u32x4 __attribute__((ext_vector_type(4)));

__device__ __forceinline__ u16 f2bf(float f) {
  unsigned int x = __float_as_uint(f);
  x = (x + 0x7fffu + ((x >> 16) & 1u)) >> 16;  // RNE
  return (u16)x;
}

__device__ __forceinline__ f32x4 mfma16(bf16x8 a, bf16x8 b, f32x4 c) {
  return __builtin_amdgcn_mfma_f32_16x16x32_bf16(a, b, c, 0, 0, 0);
}
__device__ __forceinline__ f32x16 mfma32(bf16x8 a, bf16x8 b, f32x16 c) {
  return __builtin_amdgcn_mfma_f32_32x32x16_bf16(a, b, c, 0, 0, 0);
}
// packs (lo,hi) -> u32 of 2 bf16 (low=lo), RNE
__device__ __forceinline__ u32 cvtpk_bf16(float lo, float hi) {
  u32 r;
  asm("v_cvt_pk_bf16_f32 %0, %1, %2" : "=v"(r) : "v"(lo), "v"(hi));
  return r;
}
__device__ __forceinline__ void gload_lds16(const u16* g, u16* l) {
  __builtin_amdgcn_global_load_lds((const __attribute__((address_space(1))) void*)g,
                                   (__attribute__((address_space(3))) void*)l, 16, 0, 0);
}

// ---------------- W [K][N] f32 -> WT [N][K] bf16 (all 4 weights, z-indexed) ----
__global__ __launch_bounds__(256) void wtrans_kernel(
    const float* __restrict__ W0, const float* __restrict__ W1,
    const float* __restrict__ W2, const float* __restrict__ W3,
    u16* __restrict__ T0, u16* __restrict__ T1,
    u16* __restrict__ T2, u16* __restrict__ T3) {
  __shared__ float tile[32][33];
  int z = blockIdx.z;
  const float* W = z == 0 ? W0 : z == 1 ? W1 : z == 2 ? W2 : W3;
  u16* WT = z == 0 ? T0 : z == 1 ? T1 : z == 2 ? T2 : T3;
  int k0 = blockIdx.x * 32, n0 = blockIdx.y * 32;
  int t = threadIdx.x, c = t & 31, r0 = t >> 5;
#pragma unroll
  for (int i = 0; i < 4; ++i)
    tile[r0 + i * 8][c] = W[(size_t)(k0 + r0 + i * 8) * D_ + n0 + c];
  __syncthreads();
#pragma unroll
  for (int i = 0; i < 4; ++i)
    WT[(size_t)(n0 + r0 + i * 8) * D_ + k0 + c] = f2bf(tile[c][r0 + i * 8]);
}

// ---------------- Vp [M][D] bf16 -> Vt [64 bh][64 dk][2048 s] ----------------
__global__ __launch_bounds__(256) void vtrans_kernel(const u16* __restrict__ Vp,
                                                     u16* __restrict__ Vt) {
  __shared__ u16 tile[64][65];
  int bx = blockIdx.x;  // 64 bh * 32 s-tiles
  int bh = bx >> 5;
  int s0 = (bx & 31) * 64;
  int b = bh >> 4, h = bh & 15;
  int t = threadIdx.x, c = t & 63, r0 = t >> 6;
#pragma unroll
  for (int i = 0; i < 16; ++i) {
    int s = r0 + i * 4;
    tile[s][c] = Vp[(size_t)(b * S_ + s0 + s) * D_ + h * 64 + c];
  }
  __syncthreads();
#pragma unroll
  for (int i = 0; i < 16; ++i) {
    int dk = r0 + i * 4;
    Vt[((size_t)bh * 64 + dk) * S_ + s0 + c] = tile[c][dk];
  }
}

// ---------------- Fused QKV GEMM, pipelined (raw barriers + counted vmcnt) ----
// 128x128 tile, BK=64, 4 waves. Per K-step: {barrier; ds_write A(prefetched);
// gload_lds B; issue A prefetch k+1; vmcnt(8)+lgkmcnt(0); barrier; compute}.
// The 8 A float4 loads stay in flight across the MFMA phase.
__global__ __launch_bounds__(256) void gemm_qkv_kernel(
    const float* __restrict__ Aq, const float* __restrict__ Ak, const float* __restrict__ Av,
    const u16* __restrict__ BTq, const u16* __restrict__ BTk, const u16* __restrict__ BTv,
    const float* __restrict__ bq, const float* __restrict__ bk, const float* __restrict__ bv,
    u16* __restrict__ oq, u16* __restrict__ ok, u16* __restrict__ ov) {
  __shared__ __align__(16) u16 ldsA[128 * 64];
  __shared__ __align__(16) u16 ldsB[128 * 64];
  int y = blockIdx.y;
  const float* A  = y == 0 ? Aq : y == 1 ? Ak : Av;
  const u16* BT   = y == 0 ? BTq : y == 1 ? BTk : BTv;
  const float* bias = y == 0 ? bq : y == 1 ? bk : bv;
  u16* out        = y == 0 ? oq : y == 1 ? ok : ov;

  int bx = blockIdx.x;                  // 512 = 64 Mtiles * 8 Ntiles
  int swz = (bx & 7) * 64 + (bx >> 3);  // bijective XCD swizzle (512%8==0)
  int bm = swz >> 3, bn = swz & 7;
  int t = threadIdx.x, w = t >> 6, lane = t & 63;
  int wm = w >> 1, wn = w & 1;
  int l15 = lane & 15, hi = lane >> 4;

  f32x4 acc[4][4];
#pragma unroll
  for (int m = 0; m < 4; ++m)
#pragma unroll
    for (int n = 0; n < 4; ++n) acc[m][n] = (f32x4){0.f, 0.f, 0.f, 0.f};

  // B staging: wave w owns rows [w*32, w*32+32), lane -> linear LDS via HW
  int srow = w * 32 + (lane >> 3);
  int schunk = lane & 7;
  const u16* Bg = BT + (size_t)(bn * 128 + srow) * D_ + schunk * 8;
  u16* lB = ldsB + w * 32 * 64;  // wave-uniform LDS base

  // A staging: 16 threads/row, 8 row-passes; float4 -> 4 bf16 -> ds_write_b64
  int arow = t >> 4, ac = t & 15;
  const float* Ag = A + (size_t)(bm * 128 + arow) * D_ + ac * 4;

  float4 apre[8];
#pragma unroll
  for (int p = 0; p < 8; ++p)
    apre[p] = *(const float4*)(Ag + (size_t)p * 16 * D_);

  auto compute = [&]() {
#pragma unroll
    for (int ks = 0; ks < 2; ++ks) {
      bf16x8 af[4], bfr[4];
#pragma unroll
      for (int m = 0; m < 4; ++m)
        af[m] = *(const bf16x8*)(ldsA + (wm * 64 + m * 16 + l15) * 64 + (ks * 4 + hi) * 8);
#pragma unroll
      for (int n = 0; n < 4; ++n)
        bfr[n] = *(const bf16x8*)(ldsB + (wn * 64 + n * 16 + l15) * 64 + (ks * 4 + hi) * 8);
#pragma unroll
      for (int m = 0; m < 4; ++m)
#pragma unroll
        for (int n = 0; n < 4; ++n)
          acc[m][n] = mfma16(af[m], bfr[n], acc[m][n]);
    }
  };

  for (int kk = 0; kk < D_ - 64; kk += 64) {
    asm volatile("s_waitcnt lgkmcnt(0)" ::: "memory");
    __builtin_amdgcn_s_barrier();                // LDS free (prev compute done)
    __builtin_amdgcn_sched_barrier(0);
#pragma unroll
    for (int p = 0; p < 8; ++p) {                // cvt waits apre via auto vmcnt
      u32x2 pk;
      pk[0] = cvtpk_bf16(apre[p].x, apre[p].y);
      pk[1] = cvtpk_bf16(apre[p].z, apre[p].w);
      *(u32x2*)(ldsA + (arow + p * 16) * 64 + ac * 4) = pk;
    }
    __builtin_amdgcn_sched_barrier(0);
#pragma unroll
    for (int i = 0; i < 4; ++i)                  // vmcnt 0->4 (oldest)
      gload_lds16(Bg + kk + i * 8 * D_, lB + i * 8 * 64);
    __builtin_amdgcn_sched_barrier(0);
#pragma unroll
    for (int p = 0; p < 8; ++p)                  // vmcnt 4->12 (stay in flight)
      apre[p] = *(const float4*)(Ag + kk + 64 + (size_t)p * 16 * D_);
    __builtin_amdgcn_sched_barrier(0);
    asm volatile("s_waitcnt vmcnt(8) lgkmcnt(0)" ::: "memory");  // B done, ds_writes visible
    __builtin_amdgcn_s_barrier();
    __builtin_amdgcn_sched_barrier(0);
    compute();
  }
  {  // epilogue K-step (no prefetch -> full drain)
    const int kk = D_ - 64;
    asm volatile("s_waitcnt lgkmcnt(0)" ::: "memory");
    __builtin_amdgcn_s_barrier();
    __builtin_amdgcn_sched_barrier(0);
#pragma unroll
    for (int p = 0; p < 8; ++p) {
      u32x2 pk;
      pk[0] = cvtpk_bf16(apre[p].x, apre[p].y);
      pk[1] = cvtpk_bf16(apre[p].z, apre[p].w);
      *(u32x2*)(ldsA + (arow + p * 16) * 64 + ac * 4) = pk;
    }
    __builtin_amdgcn_sched_barrier(0);
#pragma unroll
    for (int i = 0; i < 4; ++i)
      gload_lds16(Bg + kk + i * 8 * D_, lB + i * 8 * 64);
    __builtin_amdgcn_sched_barrier(0);
    asm volatile("s_waitcnt vmcnt(0) lgkmcnt(0)" ::: "memory");
    __builtin_amdgcn_s_barrier();
    __builtin_amdgcn_sched_barrier(0);
    compute();
  }

#pragma unroll
  for (int m = 0; m < 4; ++m)
#pragma unroll
    for (int n = 0; n < 4; ++n) {
      int row = bm * 128 + wm * 64 + m * 16 + hi * 4;
      int col = bn * 128 + wn * 64 + n * 16 + l15;
      float bv2 = bias[col];
#pragma unroll
      for (int r = 0; r < 4; ++r)
        out[(size_t)(row + r) * D_ + col] = f2bf(acc[m][n][r] + bv2);
    }
}

// ---------------- O-projection GEMM: d_out[M][1024] = ctx(bf16) @ WTo^T + bo --
__global__ __launch_bounds__(256) void gemm_o_kernel(const u16* __restrict__ A,
                                                     const u16* __restrict__ BT,
                                                     const float* __restrict__ bias,
                                                     float* __restrict__ out) {
  __shared__ __align__(16) u16 ldsA[128 * 64];
  __shared__ __align__(16) u16 ldsB[128 * 64];
  int bx = blockIdx.x;
  int swz = (bx & 7) * 64 + (bx >> 3);
  int bm = swz >> 3, bn = swz & 7;
  int t = threadIdx.x, w = t >> 6, lane = t & 63;
  int wm = w >> 1, wn = w & 1;
  int l15 = lane & 15, hi = lane >> 4;

  f32x4 acc[4][4];
#pragma unroll
  for (int m = 0; m < 4; ++m)
#pragma unroll
    for (int n = 0; n < 4; ++n) acc[m][n] = (f32x4){0.f, 0.f, 0.f, 0.f};

  int srow = w * 32 + (lane >> 3);
  int schunk = lane & 7;
  const u16* Ag = A + (size_t)(bm * 128 + srow) * D_ + schunk * 8;
  const u16* Bg = BT + (size_t)(bn * 128 + srow) * D_ + schunk * 8;
  u16* lA = ldsA + w * 32 * 64;
  u16* lB = ldsB + w * 32 * 64;

  for (int kk = 0; kk < D_; kk += 64) {
    __syncthreads();
#pragma unroll
    for (int i = 0; i < 4; ++i) {
      gload_lds16(Ag + kk + i * 8 * D_, lA + i * 8 * 64);
      gload_lds16(Bg + kk + i * 8 * D_, lB + i * 8 * 64);
    }
    __syncthreads();
#pragma unroll
    for (int ks = 0; ks < 2; ++ks) {
      bf16x8 af[4], bfr[4];
#pragma unroll
      for (int m = 0; m < 4; ++m)
        af[m] = *(const bf16x8*)(ldsA + (wm * 64 + m * 16 + l15) * 64 + (ks * 4 + hi) * 8);
#pragma unroll
      for (int n = 0; n < 4; ++n)
        bfr[n] = *(const bf16x8*)(ldsB + (wn * 64 + n * 16 + l15) * 64 + (ks * 4 + hi) * 8);
#pragma unroll
      for (int m = 0; m < 4; ++m)
#pragma unroll
        for (int n = 0; n < 4; ++n)
          acc[m][n] = mfma16(af[m], bfr[n], acc[m][n]);
    }
  }

#pragma unroll
  for (int m = 0; m < 4; ++m)
#pragma unroll
    for (int n = 0; n < 4; ++n) {
      int row = bm * 128 + wm * 64 + m * 16 + hi * 4;
      int col = bn * 128 + wn * 64 + n * 16 + l15;
      float bv = bias[col];
#pragma unroll
      for (int r = 0; r < 4; ++r)
        out[(size_t)(row + r) * D_ + col] = acc[m][n][r] + bv;
    }
}

// ---------------- Flash attention, 8 waves x 32 q-rows, 32x32 MFMA ----------------
// Swapped QK^T; softmax in log2 domain (Q pre-scaled by log2e/8, exp2f native).
// Defer-max (T13, THR=8 -> P<=256). Unchanged from round 8.
__global__ __launch_bounds__(512) void attn_kernel(const u16* __restrict__ Qp,
                                                   const u16* __restrict__ Kp,
                                                   const u16* __restrict__ Vt,
                                                   u16* __restrict__ ctx) {
  __shared__ __align__(16) u16 Kl[128 * 64];
  __shared__ __align__(16) u16 Vl[64 * 128];

  int bx = blockIdx.x;                 // 512 = 64 bh * 8 qtiles
  int bh = (bx & 7) * 8 + (bx >> 6);   // 8 blocks of same bh per XCD
  int qt = (bx >> 3) & 7;
  int b = bh >> 4, h = bh & 15;

  int t = threadIdx.x, w = t >> 6, lane = t & 63;
  int l31 = lane & 31, hh = lane >> 5;
  int qglob = qt * 256 + w * 32;       // wave's 32 q rows

  // Q B-frags pre-scaled by log2e/sqrt(DK) = 0.125*1.4426950 (log2-domain scores)
  bf16x8 qf[4];
  {
    const u16* qptr = Qp + (size_t)(b * S_ + qglob + l31) * D_ + h * 64;
#pragma unroll
    for (int ks = 0; ks < 4; ++ks) {
      bf16x8 v = *(const bf16x8*)(qptr + ks * 16 + hh * 8);
#pragma unroll
      for (int j = 0; j < 8; ++j) v[j] = (__bf16)((float)v[j] * 0.18033688f);
      qf[ks] = v;
    }
  }

  float m = -1e30f, l = 0.f;
  f32x16 O0, O1;
#pragma unroll
  for (int i = 0; i < 16; ++i) { O0[i] = 0.f; O1[i] = 0.f; }

  // staging (global->reg->LDS): K 128x8 chunk-slots, V 64x16; 512 threads, 2 each
  const u16* Kbase = Kp + (size_t)(b * S_) * D_ + h * 64;
  const u16* Vbase = Vt + (size_t)bh * 64 * S_;
  int krow = t >> 3, kc = t & 7;   // K rows krow, krow+64
  int vrow = t >> 4, vc = t & 15;  // V rows vrow, vrow+32
  u32x4 kreg0, kreg1, vreg0, vreg1;
  kreg0 = *(const u32x4*)(Kbase + (size_t)(krow)*D_ + kc * 8);
  kreg1 = *(const u32x4*)(Kbase + (size_t)(krow + 64) * D_ + kc * 8);
  vreg0 = *(const u32x4*)(Vbase + (size_t)(vrow)*S_ + vc * 8);
  vreg1 = *(const u32x4*)(Vbase + (size_t)(vrow + 32) * S_ + vc * 8);

  for (int kt = 0; kt < 16; ++kt) {
    __syncthreads();  // previous tile fully consumed
    // swizzled ds_writes: K chunk pi = c ^ (key&7); V pi = (c&8)|((c^dk)&7)
    *(u32x4*)(Kl + krow * 64 + ((kc ^ (krow & 7)) << 3)) = kreg0;
    *(u32x4*)(Kl + (krow + 64) * 64 + ((kc ^ (krow & 7)) << 3)) = kreg1;
    *(u32x4*)(Vl + vrow * 128 + (((vc & 8) | ((vc ^ vrow) & 7)) << 3)) = vreg0;
    *(u32x4*)(Vl + (vrow + 32) * 128 + (((vc & 8) | ((vc ^ vrow) & 7)) << 3)) = vreg1;
    if (kt < 15) {  // T14: issue next-tile loads; consumed after next barrier
      kreg0 = *(const u32x4*)(Kbase + (size_t)(kt * 128 + 128 + krow) * D_ + kc * 8);
      kreg1 = *(const u32x4*)(Kbase + (size_t)(kt * 128 + 192 + krow) * D_ + kc * 8);
      vreg0 = *(const u32x4*)(Vbase + (size_t)(vrow)*S_ + kt * 128 + 128 + vc * 8);
      vreg1 = *(const u32x4*)(Vbase + (size_t)(vrow + 32) * S_ + kt * 128 + 128 + vc * 8);
    }
    __syncthreads();  // ds_writes visible

    // ---- QK^T: 4 C-tiles of 32 keys (scores already in log2 units) ----
    f32x16 pct[4];
#pragma unroll
    for (int ct = 0; ct < 4; ++ct) {
      f32x16 p;
#pragma unroll
      for (int i = 0; i < 16; ++i) p[i] = 0.f;
#pragma unroll
      for (int ks = 0; ks < 4; ++ks) {
        int key = ct * 32 + l31;
        int cl = 2 * ks + hh;  // logical 16B chunk in K row
        bf16x8 kf = *(const bf16x8*)(Kl + key * 64 + ((cl ^ (key & 7)) << 3));
        p = mfma32(kf, qf[ks], p);
      }
      pct[ct] = p;
    }

    // ---- online softmax, log2 domain; 4-way parallel reduce chains ----
    float pm0 = -1e30f, pm1 = -1e30f, pm2 = -1e30f, pm3 = -1e30f;
#pragma unroll
    for (int i = 0; i < 16; ++i) {
      pm0 = fmaxf(pm0, pct[0][i]); pm1 = fmaxf(pm1, pct[1][i]);
      pm2 = fmaxf(pm2, pct[2][i]); pm3 = fmaxf(pm3, pct[3][i]);
    }
    float pm = fmaxf(fmaxf(pm0, pm1), fmaxf(pm2, pm3));
    pm = fmaxf(pm, __shfl_xor(pm, 32, 64));

    if (!__all(pm - m <= 8.0f)) {  // defer-max: tolerate P <= 2^8
      float mn = fmaxf(m, pm);
      float alpha = exp2f(m - mn);
      m = mn;
      l *= alpha;
#pragma unroll
      for (int i = 0; i < 16; ++i) {  // O rows are q=(i&3)+8*(i>>2)+4*hh, NOT lane-q
        float a = __shfl(alpha, (i & 3) + 8 * (i >> 2) + 4 * hh, 64);
        O0[i] *= a;
        O1[i] *= a;
      }
    }

    float ls0 = 0.f, ls1 = 0.f, ls2 = 0.f, ls3 = 0.f;
#pragma unroll
    for (int i = 0; i < 16; ++i) {
      float e0 = exp2f(pct[0][i] - m); pct[0][i] = e0; ls0 += e0;
      float e1 = exp2f(pct[1][i] - m); pct[1][i] = e1; ls1 += e1;
      float e2 = exp2f(pct[2][i] - m); pct[2][i] = e2; ls2 += e2;
      float e3 = exp2f(pct[3][i] - m); pct[3][i] = e3; ls3 += e3;
    }
    float ls = (ls0 + ls1) + (ls2 + ls3);
    l += ls + __shfl_xor(ls, 32, 64);

    // ---- repack P (T12) + PV ----
#pragma unroll
    for (int ct = 0; ct < 4; ++ct) {
#pragma unroll
      for (int ks2 = 0; ks2 < 2; ++ks2) {
        u32 A0 = cvtpk_bf16(pct[ct][8 * ks2 + 0], pct[ct][8 * ks2 + 1]);
        u32 A1 = cvtpk_bf16(pct[ct][8 * ks2 + 2], pct[ct][8 * ks2 + 3]);
        u32 B0 = cvtpk_bf16(pct[ct][8 * ks2 + 4], pct[ct][8 * ks2 + 5]);
        u32 B1 = cvtpk_bf16(pct[ct][8 * ks2 + 6], pct[ct][8 * ks2 + 7]);
        u32 s0 = __shfl_xor((int)(hh ? A0 : B0), 32, 64);
        u32 s1 = __shfl_xor((int)(hh ? A1 : B1), 32, 64);
        u32x4 fw;
        fw[0] = hh ? s0 : A0;
        fw[1] = hh ? s1 : A1;
        fw[2] = hh ? B0 : s0;
        fw[3] = hh ? B1 : s1;
        bf16x8 pf = __builtin_bit_cast(bf16x8, fw);
        int cl = ct * 4 + 2 * ks2 + hh;  // logical chunk in V row (key/8)
#pragma unroll
        for (int dkh = 0; dkh < 2; ++dkh) {
          int dk = l31 + dkh * 32;
          bf16x8 vf = *(const bf16x8*)(Vl + dk * 128 + (((cl & 8) | ((cl ^ dk) & 7)) << 3));
          if (dkh == 0) O0 = mfma32(pf, vf, O0);
          else          O1 = mfma32(pf, vf, O1);
        }
      }
    }
  }

  // ---- epilogue: normalize rows; O C-layout row q = (r&3)+8*(r>>2)+4*hh ----
#pragma unroll
  for (int r = 0; r < 16; ++r) {
    int ql = (r & 3) + 8 * (r >> 2) + 4 * hh;
    float lr = __shfl(l, ql, 64);  // l lives at lane q (both halves identical)
    float inv = 1.0f / lr;
    u16* cp = ctx + (size_t)(b * S_ + qglob + ql) * D_ + h * 64;
    cp[l31] = f2bf(O0[r] * inv);
    cp[l31 + 32] = f2bf(O1[r] * inv);
  }
}

extern "C" void kernel_launch(void* const* d_in, const int* in_sizes, int n_in,
                              void* d_out, int out_size, void* d_ws, size_t ws_size,
                              hipStream_t stream) {
  const float* query = (const float*)d_in[0];
  const float* key   = (const float*)d_in[1];
  const float* value = (const float*)d_in[2];
  const float* Wq = (const float*)d_in[3];
  const float* bq = (const float*)d_in[4];
  const float* Wk = (const float*)d_in[5];
  const float* bk = (const float*)d_in[6];
  const float* Wv = (const float*)d_in[7];
  const float* bv = (const float*)d_in[8];
  const float* Wo = (const float*)d_in[9];
  const float* bo = (const float*)d_in[10];

  char* ws = (char*)d_ws;
  const size_t WT_BYTES  = (size_t)D_ * D_ * 2;
  const size_t MAT_BYTES = (size_t)M_ * D_ * 2;
  u16* WTq = (u16*)(ws);
  u16* WTk = (u16*)(ws + WT_BYTES);
  u16* WTv = (u16*)(ws + 2 * WT_BYTES);
  u16* WTo = (u16*)(ws + 3 * WT_BYTES);
  u16* Vt  = (u16*)(ws + 4 * WT_BYTES);
  u16* Qp  = (u16*)(ws + 4 * WT_BYTES + MAT_BYTES);
  u16* Kp  = (u16*)(ws + 4 * WT_BYTES + 2 * MAT_BYTES);
  u16* Vp  = (u16*)(ws + 4 * WT_BYTES + 3 * MAT_BYTES);
  u16* ctx = Vp;   // Vp free after vtrans

  dim3 blk(256);
  wtrans_kernel<<<dim3(32, 32, 4), blk, 0, stream>>>(Wq, Wk, Wv, Wo, WTq, WTk, WTv, WTo);
  gemm_qkv_kernel<<<dim3(512, 3), blk, 0, stream>>>(query, key, value, WTq, WTk, WTv,
                                                    bq, bk, bv, Qp, Kp, Vp);
  vtrans_kernel<<<2048, blk, 0, stream>>>(Vp, Vt);
  attn_kernel<<<512, dim3(512), 0, stream>>>(Qp, Kp, Vt, ctx);
  gemm_o_kernel<<<512, blk, 0, stream>>>(ctx, WTo, bo, (float*)d_out);
}